// Round 1
// baseline (814.106 us; speedup 1.0000x reference)
//
#include <hip/hip_runtime.h>

#define EMBED 32
#define HIDDEN 64
#define NCLS 10

// ---------------- scatter layer 1: msg[dst][0:32] += embed[node_ids[src]][0:32]; cnt[dst]++ ----------------
__global__ void scatter1_kernel(const int* __restrict__ src, const int* __restrict__ dst,
                                const int* __restrict__ node_ids, const float* __restrict__ embed,
                                float* __restrict__ msg, float* __restrict__ cnt, int nEdges) {
    int t = blockIdx.x * blockDim.x + threadIdx.x;
    int e = t >> 5;          // 32 lanes per edge
    int f = t & 31;
    if (e >= nEdges) return;
    int s = src[e];
    int d = dst[e];
    float v = embed[(size_t)node_ids[s] * EMBED + f];
    atomicAdd(&msg[(size_t)d * EMBED + f], v);
    if (f == 0) atomicAdd(&cnt[d], 1.0f);
}

// ---------------- layer 1 node update: h1 = relu(agg@W1_l + b1 + x@W1_r) ----------------
__launch_bounds__(256)
__global__ void layer1_kernel(const float* __restrict__ msg, const float* __restrict__ cnt,
                              const int* __restrict__ node_ids, const float* __restrict__ embed,
                              const float* __restrict__ W1l, const float* __restrict__ b1,
                              const float* __restrict__ W1r, float* __restrict__ h1, int nNodes) {
    __shared__ float sWl[EMBED * HIDDEN];   // 8 KB
    __shared__ float sWr[EMBED * HIDDEN];   // 8 KB
    __shared__ float sAgg[4][EMBED];
    __shared__ float sX[4][EMBED];

    int tid = threadIdx.x;
    for (int i = tid; i < EMBED * HIDDEN; i += 256) { sWl[i] = W1l[i]; sWr[i] = W1r[i]; }

    int local = tid >> 6;     // 4 nodes per block
    int h     = tid & 63;     // one output feature per thread
    int n     = blockIdx.x * 4 + local;

    if (n < nNodes && h < EMBED) {
        float c = fmaxf(cnt[n], 1.0f);
        sAgg[local][h] = msg[(size_t)n * EMBED + h] / c;
        sX[local][h]   = embed[(size_t)node_ids[n] * EMBED + h];
    }
    __syncthreads();

    if (n < nNodes) {
        float acc = b1[h];
        #pragma unroll
        for (int k = 0; k < EMBED; ++k)
            acc += sAgg[local][k] * sWl[k * HIDDEN + h] + sX[local][k] * sWr[k * HIDDEN + h];
        h1[(size_t)n * HIDDEN + h] = fmaxf(acc, 0.0f);
    }
}

// ---------------- scatter layer 2: msg[dst][0:64] += h1[src][0:64] ----------------
__global__ void scatter2_kernel(const int* __restrict__ src, const int* __restrict__ dst,
                                const float* __restrict__ h1, float* __restrict__ msg, int nEdges) {
    int t = blockIdx.x * blockDim.x + threadIdx.x;
    int e = t >> 6;          // 64 lanes per edge
    int f = t & 63;
    if (e >= nEdges) return;
    float v = h1[(size_t)src[e] * HIDDEN + f];
    atomicAdd(&msg[(size_t)dst[e] * HIDDEN + f], v);
}

// ---------------- layer 2 node update fused with global mean pool (sum part) ----------------
__launch_bounds__(256)
__global__ void layer2_pool_kernel(const float* __restrict__ msg, const float* __restrict__ cnt,
                                   const float* __restrict__ h1,
                                   const float* __restrict__ W2l, const float* __restrict__ b2,
                                   const float* __restrict__ W2r, const int* __restrict__ batch,
                                   float* __restrict__ pooled, float* __restrict__ gcnt, int nNodes) {
    __shared__ float sWl[HIDDEN * HIDDEN];  // 16 KB
    __shared__ float sWr[HIDDEN * HIDDEN];  // 16 KB
    __shared__ float sAgg[4][HIDDEN];
    __shared__ float sX[4][HIDDEN];

    int tid = threadIdx.x;
    for (int i = tid; i < HIDDEN * HIDDEN; i += 256) { sWl[i] = W2l[i]; sWr[i] = W2r[i]; }

    int local = tid >> 6;
    int h     = tid & 63;
    int n     = blockIdx.x * 4 + local;

    if (n < nNodes) {
        float c = fmaxf(cnt[n], 1.0f);
        sAgg[local][h] = msg[(size_t)n * HIDDEN + h] / c;
        sX[local][h]   = h1[(size_t)n * HIDDEN + h];
    }
    __syncthreads();

    if (n < nNodes) {
        float acc = b2[h];
        #pragma unroll
        for (int k = 0; k < HIDDEN; ++k)
            acc += sAgg[local][k] * sWl[k * HIDDEN + h] + sX[local][k] * sWr[k * HIDDEN + h];
        acc = fmaxf(acc, 0.0f);               // h2 value, never materialized
        int g = batch[n];
        atomicAdd(&pooled[(size_t)g * HIDDEN + h], acc);
        if (h == 0) atomicAdd(&gcnt[g], 1.0f);
    }
}

// ---------------- classifier: out[g,c] = (pooled[g]/gcnt[g]) @ W_out + b_out ----------------
__global__ void out_kernel(const float* __restrict__ pooled, const float* __restrict__ gcnt,
                           const float* __restrict__ Wout, const float* __restrict__ bout,
                           float* __restrict__ out, int nGraphs) {
    int i = blockIdx.x * blockDim.x + threadIdx.x;
    if (i >= nGraphs * NCLS) return;
    int g = i / NCLS;
    int c = i % NCLS;
    float inv = 1.0f / fmaxf(gcnt[g], 1.0f);
    float acc = bout[c];
    #pragma unroll
    for (int k = 0; k < HIDDEN; ++k)
        acc += pooled[(size_t)g * HIDDEN + k] * inv * Wout[k * NCLS + c];
    out[i] = acc;
}

extern "C" void kernel_launch(void* const* d_in, const int* in_sizes, int n_in,
                              void* d_out, int out_size, void* d_ws, size_t ws_size,
                              hipStream_t stream) {
    const int*   node_ids = (const int*)d_in[0];
    const int*   src      = (const int*)d_in[1];
    const int*   dst      = (const int*)d_in[2];
    const int*   batch    = (const int*)d_in[3];
    const float* embed    = (const float*)d_in[4];
    const float* W1l      = (const float*)d_in[5];
    const float* b1       = (const float*)d_in[6];
    const float* W1r      = (const float*)d_in[7];
    const float* W2l      = (const float*)d_in[8];
    const float* b2       = (const float*)d_in[9];
    const float* W2r      = (const float*)d_in[10];
    const float* Wout     = (const float*)d_in[11];
    const float* bout     = (const float*)d_in[12];

    const int N = in_sizes[0];          // 100000 nodes
    const int E = in_sizes[1];          // 1200000 edges
    const int G = out_size / NCLS;      // 1024 graphs

    // workspace layout (floats): msg[N*64] | cnt[N] | h1[N*64] | pooled[G*64] | gcnt[G]
    float* msg    = (float*)d_ws;
    float* cnt    = msg + (size_t)N * HIDDEN;
    float* h1     = cnt + N;
    float* pooled = h1 + (size_t)N * HIDDEN;
    float* gcnt   = pooled + (size_t)G * HIDDEN;

    float* out = (float*)d_out;

    // ---- layer 1 ----
    hipMemsetAsync(msg, 0, (size_t)N * EMBED * sizeof(float), stream);
    hipMemsetAsync(cnt, 0, (size_t)N * sizeof(float), stream);
    {
        long long threads = (long long)E * 32;
        int grid = (int)((threads + 255) / 256);
        scatter1_kernel<<<grid, 256, 0, stream>>>(src, dst, node_ids, embed, msg, cnt, E);
    }
    layer1_kernel<<<(N + 3) / 4, 256, 0, stream>>>(msg, cnt, node_ids, embed, W1l, b1, W1r, h1, N);

    // ---- layer 2 (reuse msg buffer; cnt is the same graph degree) ----
    hipMemsetAsync(msg, 0, (size_t)N * HIDDEN * sizeof(float), stream);
    {
        long long threads = (long long)E * 64;
        int grid = (int)((threads + 255) / 256);
        scatter2_kernel<<<grid, 256, 0, stream>>>(src, dst, h1, msg, E);
    }
    hipMemsetAsync(pooled, 0, (size_t)G * HIDDEN * sizeof(float), stream);
    hipMemsetAsync(gcnt, 0, (size_t)G * sizeof(float), stream);
    layer2_pool_kernel<<<(N + 3) / 4, 256, 0, stream>>>(msg, cnt, h1, W2l, b2, W2r, batch,
                                                        pooled, gcnt, N);

    // ---- classifier ----
    out_kernel<<<(G * NCLS + 255) / 256, 256, 0, stream>>>(pooled, gcnt, Wout, bout, out, G);
}

// Round 3
// 735.611 us; speedup vs baseline: 1.1067x; 1.1067x over previous
//
#include <hip/hip_runtime.h>

#define EMBED 32
#define HIDDEN 64
#define NCLS 10

// ============ CSR construction ============

__global__ void deg_kernel(const int* __restrict__ dst, int* __restrict__ deg, int nEdges) {
    int e = blockIdx.x * blockDim.x + threadIdx.x;
    if (e >= nEdges) return;
    atomicAdd(&deg[dst[e]], 1);
}

// per-256-chunk sums
__global__ void block_sum_kernel(const int* __restrict__ deg, int* __restrict__ blockSums, int n) {
    __shared__ int s[256];
    int i = blockIdx.x * 256 + threadIdx.x;
    s[threadIdx.x] = (i < n) ? deg[i] : 0;
    __syncthreads();
    for (int off = 128; off > 0; off >>= 1) {
        if (threadIdx.x < off) s[threadIdx.x] += s[threadIdx.x + off];
        __syncthreads();
    }
    if (threadIdx.x == 0) blockSums[blockIdx.x] = s[0];
}

// tiny serial exclusive scan of chunk sums (nb ~ 391)
__global__ void scan_sums_kernel(int* blockSums, int nb) {
    if (blockIdx.x == 0 && threadIdx.x == 0) {
        int acc = 0;
        for (int i = 0; i < nb; ++i) { int v = blockSums[i]; blockSums[i] = acc; acc += v; }
    }
}

// local exclusive scan + chunk offset -> rowptr (start index per node)
__global__ void scan_local_kernel(const int* __restrict__ deg, const int* __restrict__ blockSums,
                                  int* __restrict__ rowptr, int n) {
    __shared__ int s[256];
    int i = blockIdx.x * 256 + threadIdx.x;
    int v = (i < n) ? deg[i] : 0;
    s[threadIdx.x] = v;
    __syncthreads();
    for (int off = 1; off < 256; off <<= 1) {
        int t = (threadIdx.x >= off) ? s[threadIdx.x - off] : 0;
        __syncthreads();
        s[threadIdx.x] += t;
        __syncthreads();
    }
    if (i < n) rowptr[i] = blockSums[blockIdx.x] + s[threadIdx.x] - v;  // exclusive
}

__global__ void fill_kernel(const int* __restrict__ src, const int* __restrict__ dst,
                            const int* __restrict__ rowptr, int* __restrict__ cursor,
                            int* __restrict__ nbr, int nEdges) {
    int e = blockIdx.x * blockDim.x + threadIdx.x;
    if (e >= nEdges) return;
    int d = dst[e];
    int pos = atomicAdd(&cursor[d], 1);
    nbr[rowptr[d] + pos] = src[e];
}

// ============ Layer 1: gather(embed[node_ids[nbr]]) mean + relu(agg@W1l + b1 + x@W1r) ============
__launch_bounds__(256)
__global__ void layer1_fused(const int* __restrict__ nbr, const int* __restrict__ rowptr,
                             const int* __restrict__ deg, const int* __restrict__ node_ids,
                             const float* __restrict__ embed,
                             const float* __restrict__ W1l, const float* __restrict__ b1,
                             const float* __restrict__ W1r, float* __restrict__ h1, int nNodes) {
    __shared__ float sWl[EMBED * HIDDEN];   // 8 KB
    __shared__ float sWr[EMBED * HIDDEN];   // 8 KB
    __shared__ float sAgg[4][EMBED];
    __shared__ float sX[4][EMBED];

    int tid = threadIdx.x;
    for (int i = tid; i < EMBED * HIDDEN; i += 256) { sWl[i] = W1l[i]; sWr[i] = W1r[i]; }

    int local = tid >> 6;     // wave id: 4 nodes per block
    int lane  = tid & 63;
    int n     = blockIdx.x * 4 + local;

    if (n < nNodes) {
        int dg = deg[n], start = rowptr[n];
        int half = lane >> 5;  // two edges in flight per wave
        int f    = lane & 31;
        float sum = 0.f;
        for (int j = half; j < dg; j += 2) {
            int nb = nbr[start + j];
            sum += embed[(size_t)node_ids[nb] * EMBED + f];
        }
        sum += __shfl_xor(sum, 32);
        if (half == 0) {
            sAgg[local][f] = sum / fmaxf((float)dg, 1.f);
            sX[local][f]   = embed[(size_t)node_ids[n] * EMBED + f];
        }
    }
    __syncthreads();

    if (n < nNodes) {
        int h = lane;
        float acc = b1[h];
        #pragma unroll
        for (int k = 0; k < EMBED; ++k)
            acc += sAgg[local][k] * sWl[k * HIDDEN + h] + sX[local][k] * sWr[k * HIDDEN + h];
        h1[(size_t)n * HIDDEN + h] = fmaxf(acc, 0.f);
    }
}

// ============ Layer 2: gather(h1[nbr]) mean + relu(agg@W2l + b2 + x@W2r), fused with pool ============
__launch_bounds__(256)
__global__ void layer2_fused(const int* __restrict__ nbr, const int* __restrict__ rowptr,
                             const int* __restrict__ deg, const float* __restrict__ h1,
                             const float* __restrict__ W2l, const float* __restrict__ b2,
                             const float* __restrict__ W2r, const int* __restrict__ batch,
                             float* __restrict__ pooled, float* __restrict__ gcnt, int nNodes) {
    __shared__ float sWl[HIDDEN * HIDDEN];  // 16 KB
    __shared__ float sWr[HIDDEN * HIDDEN];  // 16 KB
    __shared__ float sAgg[4][HIDDEN];
    __shared__ float sX[4][HIDDEN];

    int tid = threadIdx.x;
    for (int i = tid; i < HIDDEN * HIDDEN; i += 256) { sWl[i] = W2l[i]; sWr[i] = W2r[i]; }

    int local = tid >> 6;
    int h     = tid & 63;
    int n     = blockIdx.x * 4 + local;

    if (n < nNodes) {
        int dg = deg[n], start = rowptr[n];
        float sum = 0.f;
        for (int j = 0; j < dg; ++j) {
            int nb = nbr[start + j];
            sum += h1[(size_t)nb * HIDDEN + h];   // 64 lanes -> coalesced 256B row
        }
        sAgg[local][h] = sum / fmaxf((float)dg, 1.f);
        sX[local][h]   = h1[(size_t)n * HIDDEN + h];
    }
    __syncthreads();

    if (n < nNodes) {
        float acc = b2[h];
        #pragma unroll
        for (int k = 0; k < HIDDEN; ++k)
            acc += sAgg[local][k] * sWl[k * HIDDEN + h] + sX[local][k] * sWr[k * HIDDEN + h];
        acc = fmaxf(acc, 0.f);                // h2, never materialized
        int g = batch[n];
        atomicAdd(&pooled[(size_t)g * HIDDEN + h], acc);
        if (h == 0) atomicAdd(&gcnt[g], 1.f);
    }
}

// ============ classifier ============
__global__ void out_kernel(const float* __restrict__ pooled, const float* __restrict__ gcnt,
                           const float* __restrict__ Wout, const float* __restrict__ bout,
                           float* __restrict__ out, int nGraphs) {
    int i = blockIdx.x * blockDim.x + threadIdx.x;
    if (i >= nGraphs * NCLS) return;
    int g = i / NCLS;
    int c = i % NCLS;
    float inv = 1.0f / fmaxf(gcnt[g], 1.0f);
    float acc = bout[c];
    #pragma unroll
    for (int k = 0; k < HIDDEN; ++k)
        acc += pooled[(size_t)g * HIDDEN + k] * inv * Wout[k * NCLS + c];
    out[i] = acc;
}

extern "C" void kernel_launch(void* const* d_in, const int* in_sizes, int n_in,
                              void* d_out, int out_size, void* d_ws, size_t ws_size,
                              hipStream_t stream) {
    const int*   node_ids = (const int*)d_in[0];
    const int*   src      = (const int*)d_in[1];
    const int*   dst      = (const int*)d_in[2];
    const int*   batch    = (const int*)d_in[3];
    const float* embed    = (const float*)d_in[4];
    const float* W1l      = (const float*)d_in[5];
    const float* b1       = (const float*)d_in[6];
    const float* W1r      = (const float*)d_in[7];
    const float* W2l      = (const float*)d_in[8];
    const float* b2       = (const float*)d_in[9];
    const float* W2r      = (const float*)d_in[10];
    const float* Wout     = (const float*)d_in[11];
    const float* bout     = (const float*)d_in[12];

    const int N = in_sizes[0];          // 100000
    const int E = in_sizes[1];          // 1200000
    const int G = out_size / NCLS;      // 1024
    const int NB = (N + 255) / 256;     // scan chunks

    // workspace layout:
    // deg[N] | rowptr[N] | cursor[N] | blockSums[NB] | nbr[E]  (ints)
    // h1[N*64] | pooled[G*64] | gcnt[G]                        (floats)
    int* deg       = (int*)d_ws;
    int* rowptr    = deg + N;
    int* cursor    = rowptr + N;
    int* blockSums = cursor + N;
    int* nbr       = blockSums + ((NB + 63) & ~63);
    float* h1      = (float*)(nbr + ((E + 63) & ~63));
    float* pooled  = h1 + (size_t)N * HIDDEN;
    float* gcnt    = pooled + (size_t)G * HIDDEN;

    float* out = (float*)d_out;

    // ---- CSR build ----
    hipMemsetAsync(deg, 0, (size_t)N * sizeof(int), stream);
    hipMemsetAsync(cursor, 0, (size_t)N * sizeof(int), stream);
    deg_kernel<<<(E + 255) / 256, 256, 0, stream>>>(dst, deg, E);
    block_sum_kernel<<<NB, 256, 0, stream>>>(deg, blockSums, N);
    scan_sums_kernel<<<1, 1, 0, stream>>>(blockSums, NB);
    scan_local_kernel<<<NB, 256, 0, stream>>>(deg, blockSums, rowptr, N);
    fill_kernel<<<(E + 255) / 256, 256, 0, stream>>>(src, dst, rowptr, cursor, nbr, E);

    // ---- layer 1 (fused gather + GEMM) ----
    layer1_fused<<<(N + 3) / 4, 256, 0, stream>>>(nbr, rowptr, deg, node_ids, embed,
                                                  W1l, b1, W1r, h1, N);

    // ---- layer 2 (fused gather + GEMM + pool) ----
    hipMemsetAsync(pooled, 0, (size_t)G * HIDDEN * sizeof(float), stream);
    hipMemsetAsync(gcnt, 0, (size_t)G * sizeof(float), stream);
    layer2_fused<<<(N + 3) / 4, 256, 0, stream>>>(nbr, rowptr, deg, h1, W2l, b2, W2r,
                                                  batch, pooled, gcnt, N);

    // ---- classifier ----
    out_kernel<<<(G * NCLS + 255) / 256, 256, 0, stream>>>(pooled, gcnt, Wout, bout, out, G);
}

// Round 6
// 641.464 us; speedup vs baseline: 1.2691x; 1.1468x over previous
//
#include <hip/hip_runtime.h>

#define EMBED 32
#define HIDDEN 64
#define NCLS 10

// ============ CSR construction (unchanged, proven) ============

__global__ void deg_kernel(const int* __restrict__ dst, int* __restrict__ deg, int nEdges) {
    int e = blockIdx.x * blockDim.x + threadIdx.x;
    if (e >= nEdges) return;
    atomicAdd(&deg[dst[e]], 1);
}

__global__ void block_sum_kernel(const int* __restrict__ deg, int* __restrict__ blockSums, int n) {
    __shared__ int s[256];
    int i = blockIdx.x * 256 + threadIdx.x;
    s[threadIdx.x] = (i < n) ? deg[i] : 0;
    __syncthreads();
    for (int off = 128; off > 0; off >>= 1) {
        if (threadIdx.x < off) s[threadIdx.x] += s[threadIdx.x + off];
        __syncthreads();
    }
    if (threadIdx.x == 0) blockSums[blockIdx.x] = s[0];
}

__global__ void scan_sums_kernel(int* blockSums, int nb) {
    if (blockIdx.x == 0 && threadIdx.x == 0) {
        int acc = 0;
        for (int i = 0; i < nb; ++i) { int v = blockSums[i]; blockSums[i] = acc; acc += v; }
    }
}

__global__ void scan_local_kernel(const int* __restrict__ deg, const int* __restrict__ blockSums,
                                  int* __restrict__ rowptr, int n) {
    __shared__ int s[256];
    int i = blockIdx.x * 256 + threadIdx.x;
    int v = (i < n) ? deg[i] : 0;
    s[threadIdx.x] = v;
    __syncthreads();
    for (int off = 1; off < 256; off <<= 1) {
        int t = (threadIdx.x >= off) ? s[threadIdx.x - off] : 0;
        __syncthreads();
        s[threadIdx.x] += t;
        __syncthreads();
    }
    if (i < n) rowptr[i] = blockSums[blockIdx.x] + s[threadIdx.x] - v;  // exclusive
}

__global__ void fill_kernel(const int* __restrict__ src, const int* __restrict__ dst,
                            const int* __restrict__ rowptr, int* __restrict__ cursor,
                            int* __restrict__ nbr, int nEdges) {
    int e = blockIdx.x * blockDim.x + threadIdx.x;
    if (e >= nEdges) return;
    int d = dst[e];
    int pos = atomicAdd(&cursor[d], 1);
    nbr[rowptr[d] + pos] = src[e];
}

// ============ Layer 1: wave-per-node, feature-per-lane, unrolled gather, readlane GEMM ============
__launch_bounds__(512)
__global__ void layer1_fused(const int* __restrict__ nbr, const int* __restrict__ rowptr,
                             const int* __restrict__ deg, const int* __restrict__ node_ids,
                             const float* __restrict__ embed,
                             const float* __restrict__ W1l, const float* __restrict__ b1,
                             const float* __restrict__ W1r, float* __restrict__ h1, int nNodes) {
    __shared__ float sWl[EMBED * HIDDEN];   // 8 KB, read-only after staging
    __shared__ float sWr[EMBED * HIDDEN];   // 8 KB

    int tid = threadIdx.x;
    for (int i = tid; i < EMBED * HIDDEN; i += 512) { sWl[i] = W1l[i]; sWr[i] = W1r[i]; }
    __syncthreads();           // only barrier; nothing below writes LDS

    int wave = tid >> 6;
    int lane = tid & 63;
    int half = lane >> 5;      // 2 halves process alternating edges
    int f    = lane & 31;
    float bias = b1[lane];

    for (int n = blockIdx.x * 8 + wave; n < nNodes; n += gridDim.x * 8) {
        int dg = deg[n], start = rowptr[n];
        float xv = embed[(size_t)node_ids[n] * EMBED + f];

        // mean over neighbors: 2 halves x unroll 2 = 4 rows in flight
        float s0 = 0.f, s1 = 0.f;
        int j = half;
        for (; j + 2 < dg; j += 4) {
            int n0 = nbr[start + j];
            int n1 = nbr[start + j + 2];
            s0 += embed[(size_t)node_ids[n0] * EMBED + f];
            s1 += embed[(size_t)node_ids[n1] * EMBED + f];
        }
        for (; j < dg; j += 2)
            s0 += embed[(size_t)node_ids[nbr[start + j]] * EMBED + f];
        float sum = s0 + s1;
        sum += __shfl_xor(sum, 32);                 // all lanes now hold total for feature f
        float aggv = sum / fmaxf((float)dg, 1.f);

        // GEMM: out feature = lane; broadcast feature k from lane k (literal -> v_readlane)
        float acc = bias;
        #pragma unroll
        for (int k = 0; k < EMBED; ++k) {
            float a = __shfl(aggv, k);
            float x = __shfl(xv, k);
            acc += a * sWl[k * HIDDEN + lane] + x * sWr[k * HIDDEN + lane];
        }
        h1[(size_t)n * HIDDEN + lane] = fmaxf(acc, 0.f);
    }
}

// ============ Layer 2: wave-per-node, feature-per-lane, unroll-4 gather, fused pool ============
__launch_bounds__(512)
__global__ void layer2_fused(const int* __restrict__ nbr, const int* __restrict__ rowptr,
                             const int* __restrict__ deg, const float* __restrict__ h1,
                             const float* __restrict__ W2l, const float* __restrict__ b2,
                             const float* __restrict__ W2r, const int* __restrict__ batch,
                             float* __restrict__ pooled, float* __restrict__ gcnt, int nNodes) {
    __shared__ float sWl[HIDDEN * HIDDEN];  // 16 KB, read-only after staging
    __shared__ float sWr[HIDDEN * HIDDEN];  // 16 KB

    int tid = threadIdx.x;
    for (int i = tid; i < HIDDEN * HIDDEN; i += 512) { sWl[i] = W2l[i]; sWr[i] = W2r[i]; }
    __syncthreads();           // only barrier

    int wave = tid >> 6;
    int lane = tid & 63;
    float bias = b2[lane];

    for (int n = blockIdx.x * 8 + wave; n < nNodes; n += gridDim.x * 8) {
        int dg = deg[n], start = rowptr[n];
        int g = batch[n];
        float xv = h1[(size_t)n * HIDDEN + lane];

        // mean over neighbors: 4 independent accumulators = 4 coalesced rows in flight
        float s0 = 0.f, s1 = 0.f, s2 = 0.f, s3 = 0.f;
        int j = 0;
        for (; j + 3 < dg; j += 4) {
            int n0 = nbr[start + j];
            int n1 = nbr[start + j + 1];
            int n2 = nbr[start + j + 2];
            int n3 = nbr[start + j + 3];
            s0 += h1[(size_t)n0 * HIDDEN + lane];
            s1 += h1[(size_t)n1 * HIDDEN + lane];
            s2 += h1[(size_t)n2 * HIDDEN + lane];
            s3 += h1[(size_t)n3 * HIDDEN + lane];
        }
        for (; j < dg; ++j)
            s0 += h1[(size_t)nbr[start + j] * HIDDEN + lane];
        float aggv = ((s0 + s1) + (s2 + s3)) / fmaxf((float)dg, 1.f);

        float acc = bias;
        #pragma unroll
        for (int k = 0; k < HIDDEN; ++k) {
            float a = __shfl(aggv, k);
            float x = __shfl(xv, k);
            acc += a * sWl[k * HIDDEN + lane] + x * sWr[k * HIDDEN + lane];
        }
        acc = fmaxf(acc, 0.f);                      // h2, never materialized
        atomicAdd(&pooled[(size_t)g * HIDDEN + lane], acc);
        if (lane == 0) atomicAdd(&gcnt[g], 1.f);
    }
}

// ============ classifier ============
__global__ void out_kernel(const float* __restrict__ pooled, const float* __restrict__ gcnt,
                           const float* __restrict__ Wout, const float* __restrict__ bout,
                           float* __restrict__ out, int nGraphs) {
    int i = blockIdx.x * blockDim.x + threadIdx.x;
    if (i >= nGraphs * NCLS) return;
    int g = i / NCLS;
    int c = i % NCLS;
    float inv = 1.0f / fmaxf(gcnt[g], 1.0f);
    float acc = bout[c];
    #pragma unroll
    for (int k = 0; k < HIDDEN; ++k)
        acc += pooled[(size_t)g * HIDDEN + k] * inv * Wout[k * NCLS + c];
    out[i] = acc;
}

extern "C" void kernel_launch(void* const* d_in, const int* in_sizes, int n_in,
                              void* d_out, int out_size, void* d_ws, size_t ws_size,
                              hipStream_t stream) {
    const int*   node_ids = (const int*)d_in[0];
    const int*   src      = (const int*)d_in[1];
    const int*   dst      = (const int*)d_in[2];
    const int*   batch    = (const int*)d_in[3];
    const float* embed    = (const float*)d_in[4];
    const float* W1l      = (const float*)d_in[5];
    const float* b1       = (const float*)d_in[6];
    const float* W1r      = (const float*)d_in[7];
    const float* W2l      = (const float*)d_in[8];
    const float* b2       = (const float*)d_in[9];
    const float* W2r      = (const float*)d_in[10];
    const float* Wout     = (const float*)d_in[11];
    const float* bout     = (const float*)d_in[12];

    const int N = in_sizes[0];          // 100000
    const int E = in_sizes[1];          // 1200000
    const int G = out_size / NCLS;      // 1024
    const int NB = (N + 255) / 256;

    // workspace: deg[N] | rowptr[N] | cursor[N] | blockSums[pad NB] | nbr[pad E] (ints)
    //            h1[N*64] | pooled[G*64] | gcnt[G] (floats)
    int* deg       = (int*)d_ws;
    int* rowptr    = deg + N;
    int* cursor    = rowptr + N;
    int* blockSums = cursor + N;
    int* nbr       = blockSums + ((NB + 63) & ~63);
    float* h1      = (float*)(nbr + ((E + 63) & ~63));
    float* pooled  = h1 + (size_t)N * HIDDEN;
    float* gcnt    = pooled + (size_t)G * HIDDEN;

    float* out = (float*)d_out;

    // ---- CSR build ----
    hipMemsetAsync(deg, 0, (size_t)N * sizeof(int), stream);
    hipMemsetAsync(cursor, 0, (size_t)N * sizeof(int), stream);
    deg_kernel<<<(E + 255) / 256, 256, 0, stream>>>(dst, deg, E);
    block_sum_kernel<<<NB, 256, 0, stream>>>(deg, blockSums, N);
    scan_sums_kernel<<<1, 1, 0, stream>>>(blockSums, NB);
    scan_local_kernel<<<NB, 256, 0, stream>>>(deg, blockSums, rowptr, N);
    fill_kernel<<<(E + 255) / 256, 256, 0, stream>>>(src, dst, rowptr, cursor, nbr, E);

    // ---- layer 1 ----
    layer1_fused<<<1024, 512, 0, stream>>>(nbr, rowptr, deg, node_ids, embed,
                                           W1l, b1, W1r, h1, N);

    // ---- layer 2 + pool ----
    hipMemsetAsync(pooled, 0, (size_t)G * HIDDEN * sizeof(float), stream);
    hipMemsetAsync(gcnt, 0, (size_t)G * sizeof(float), stream);
    layer2_fused<<<1024, 512, 0, stream>>>(nbr, rowptr, deg, h1, W2l, b2, W2r,
                                           batch, pooled, gcnt, N);

    // ---- classifier ----
    out_kernel<<<(G * NCLS + 255) / 256, 256, 0, stream>>>(pooled, gcnt, Wout, bout, out, G);
}